// Round 1
// baseline (279.040 us; speedup 1.0000x reference)
//
#include <hip/hip_runtime.h>
#include <cstddef>

// Problem constants
#define NB 16
#define NVOX 128
#define NPT 1920
#define NPAIRS 32768   // 16 b * 16 tz * 16 ty * 8 x-pairs

static __device__ __forceinline__ float2 f2(float a, float b) {
    float2 r; r.x = a; r.y = b; return r;
}

// ---------------------------------------------------------------------------
// Stage 1: Conv1d(256,240,1) on the (256,8) view, all 16 batches.
// One block per output channel o (240 blocks). w1 row staged coalesced in LDS;
// thread = (half, b, l) computes a split-K partial; pair-combined at the end.
// x1g layout: [b][o*8+l]  (matches (240,8) == (64,30) flat view downstream).
// ---------------------------------------------------------------------------
__global__ __launch_bounds__(256)
void mlp_stage1(const float* __restrict__ q, const float* __restrict__ w1,
                const float* __restrict__ b1, float* __restrict__ x1g)
{
    __shared__ float wrow[256];
    __shared__ float psum[256];
    const int o = blockIdx.x;
    const int t = threadIdx.x;

    wrow[t] = w1[o * 256 + t];
    __syncthreads();

    const int half = t >> 7;       // K-split: i in [half*128, half*128+128)
    const int bl = t & 127;
    const int b = bl >> 3, l = bl & 7;
    const float* qb = q + b * 2048 + l + half * 1024;  // q[b][i*8+l]
    float s = 0.f;
    #pragma unroll 8
    for (int i = 0; i < 128; ++i)
        s = fmaf(wrow[half * 128 + i], qb[i * 8], s);
    psum[t] = s;
    __syncthreads();

    if (t < 128) {
        int bb = t >> 3, ll = t & 7;
        x1g[bb * 1920 + o * 8 + ll] = b1[o] + psum[t] + psum[t + 128];
    }
}

// ---------------------------------------------------------------------------
// Tail: IN chains + grouped convs + point generation + active-tile flags.
// One block per batch, 256 threads. Parallel group reductions (G threads per
// channel, stride-G element access -> conflict-light).
// ---------------------------------------------------------------------------
__global__ __launch_bounds__(256)
void mlp_tail(const float* __restrict__ x1g, const float* __restrict__ qval,
              const float* __restrict__ w2, const float* __restrict__ b2,
              const float* __restrict__ w3, const float* __restrict__ b3,
              const float* __restrict__ w4, const float* __restrict__ b4,
              const float* __restrict__ w5, const float* __restrict__ b5,
              float4* __restrict__ pts, unsigned char* __restrict__ flags)
{
    __shared__ float bufA[7680];
    __shared__ float bufC[3840];
    __shared__ float psum[256], psq[256];
    __shared__ float meanv[64], rstdv[64];
    __shared__ float m4[16], r4[16];

    const int b = blockIdx.x;
    const int t = threadIdx.x;

    for (int u = t; u < 1920; u += 256) bufA[u] = x1g[b * 1920 + u];
    __syncthreads();

    // IN1 over (64,30): 4 threads/channel
    {
        int c = t >> 2, g = t & 3;
        float s = 0.f, s2 = 0.f;
        for (int p = g; p < 30; p += 4) { float v = bufA[c * 30 + p]; s += v; s2 += v * v; }
        psum[t] = s; psq[t] = s2;
    }
    __syncthreads();
    if (t < 64) {
        float s = 0.f, s2 = 0.f;
        for (int g = 0; g < 4; ++g) { s += psum[t * 4 + g]; s2 += psq[t * 4 + g]; }
        float m = s * (1.f / 30.f);
        float var = s2 * (1.f / 30.f) - m * m;
        meanv[t] = m; rstdv[t] = rsqrtf(var + 1e-5f);
    }
    __syncthreads();
    for (int k = t; k < 1920; k += 256) {
        int c = k / 30;
        bufA[k] = fmaxf((bufA[k] - meanv[c]) * rstdv[c], 0.f);
    }
    __syncthreads();

    // stage2: grouped conv 64->128, flat (32,120) in bufC
    for (int m = t; m < 3840; m += 256) {
        int c = m / 60;
        int r = m - c * 60;
        int j = r / 30;
        int p = r - j * 30;
        bufC[m] = fmaf(bufA[c * 30 + p], w2[c * 2 + j], b2[c * 2 + j]);
    }
    __syncthreads();
    // IN2 over (32,120): 8 threads/channel
    {
        int c = t >> 3, g = t & 7;
        float s = 0.f, s2 = 0.f;
        for (int p = g; p < 120; p += 8) { float v = bufC[c * 120 + p]; s += v; s2 += v * v; }
        psum[t] = s; psq[t] = s2;
    }
    __syncthreads();
    if (t < 32) {
        float s = 0.f, s2 = 0.f;
        for (int g = 0; g < 8; ++g) { s += psum[t * 8 + g]; s2 += psq[t * 8 + g]; }
        float m = s * (1.f / 120.f);
        float var = s2 * (1.f / 120.f) - m * m;
        meanv[t] = m; rstdv[t] = rsqrtf(var + 1e-5f);
    }
    __syncthreads();
    for (int m = t; m < 3840; m += 256) {
        int c = m / 120;
        bufC[m] = fmaxf((bufC[m] - meanv[c]) * rstdv[c], 0.f);
    }
    __syncthreads();

    // stage3: grouped conv 32->64, flat (16,480) in bufA
    for (int m = t; m < 7680; m += 256) {
        int c = m / 240;
        int r = m - c * 240;
        int j = r / 120;
        int p = r - j * 120;
        bufA[m] = fmaf(bufC[c * 120 + p], w3[c * 2 + j], b3[c * 2 + j]);
    }
    __syncthreads();

    // IN3 over (16,480): 16 threads/channel, 30 elems each
    const int c3 = t >> 4, g3 = t & 15;
    {
        float s = 0.f, s2 = 0.f;
        for (int k = 0; k < 30; ++k) { float v = bufA[c3 * 480 + g3 + 16 * k]; s += v; s2 += v * v; }
        psum[t] = s; psq[t] = s2;
    }
    __syncthreads();
    if (t < 16) {
        float s = 0.f, s2 = 0.f;
        for (int g = 0; g < 16; ++g) { s += psum[t * 16 + g]; s2 += psq[t * 16 + g]; }
        float m = s * (1.f / 480.f);
        float var = s2 * (1.f / 480.f) - m * m;
        meanv[t] = m; rstdv[t] = rsqrtf(var + 1e-5f);
    }
    __syncthreads();
    // normalize+relu in place, accumulate relu'd sums for stage4 stats
    {
        float m = meanv[c3], r = rstdv[c3];
        float s = 0.f, s2 = 0.f;
        for (int k = 0; k < 30; ++k) {
            int idx = c3 * 480 + g3 + 16 * k;
            float v = fmaxf((bufA[idx] - m) * r, 0.f);
            bufA[idx] = v; s += v; s2 += v * v;
        }
        psum[t] = s; psq[t] = s2;
    }
    __syncthreads();
    // stage4 IN stats analytically: x4[c, j*480+p] = x3n[c,p]*w4[c,j]+b4[c*4+j]
    if (t < 16) {
        float s = 0.f, s2 = 0.f;
        for (int g = 0; g < 16; ++g) { s += psum[t * 16 + g]; s2 += psq[t * 16 + g]; }
        float sum4 = 0.f, sq4 = 0.f;
        for (int j = 0; j < 4; ++j) {
            float w = w4[t * 4 + j], bb = b4[t * 4 + j];
            sum4 += w * s + 480.f * bb;
            sq4  += w * w * s2 + 2.f * w * bb * s + 480.f * bb * bb;
        }
        float m = sum4 * (1.f / 1920.f);
        float var = sq4 * (1.f / 1920.f) - m * m;
        m4[t] = m; r4[t] = rsqrtf(var + 1e-5f);
    }
    __syncthreads();

    // per-point: stage4 apply + stage5 einsum + tanh + emit point + mark tiles
    for (int l = t; l < NPT; l += 256) {
        int j = l / 480;
        int p = l - j * 480;
        float a0 = b5[0], a1 = b5[1], a2 = b5[2];
        #pragma unroll
        for (int c = 0; c < 16; ++c) {
            float xv = bufA[c * 480 + p];
            float x4 = fmaf(xv, w4[c * 4 + j], b4[c * 4 + j]);
            float h  = fmaxf((x4 - m4[c]) * r4[c], 0.f);
            a0 = fmaf(w5[c],      h, a0);
            a1 = fmaf(w5[16 + c], h, a1);
            a2 = fmaf(w5[32 + c], h, a2);
        }
        float px = tanhf(a0) * 64.f + 63.5f;
        float py = tanhf(a1) * 64.f + 63.5f;
        float pz = tanhf(a2) * 64.f + 63.5f;
        float val = 1.f / (1.f + expf(-qval[l]));

        float4 pv; pv.x = px; pv.y = py; pv.z = pz; pv.w = val;
        pts[b * NPT + l] = pv;

        int x0 = (int)floorf(px), y0 = (int)floorf(py), z0 = (int)floorf(pz);
        int xlo = max(0, x0 - 3), xhi = min(127, x0 + 4);
        int ylo = max(0, y0 - 3), yhi = min(127, y0 + 4);
        int zlo = max(0, z0 - 3), zhi = min(127, z0 + 4);
        if (xlo > xhi || ylo > yhi || zlo > zhi) continue;
        int txl = xlo >> 3, txh = xhi >> 3;
        int tyl = ylo >> 3, tyh = yhi >> 3;
        int tzl = zlo >> 3, tzh = zhi >> 3;
        for (int tz = tzl; tz <= tzh; ++tz)
            for (int ty = tyl; ty <= tyh; ++ty)
                for (int tx = txl; tx <= txh; ++tx)
                    flags[((b * 16 + tz) * 16 + ty) * 16 + tx] = 1;
    }
}

// ---------------------------------------------------------------------------
// Per-axis composed 7-tap coefficients (A^3, zero-padded 3-tap average):
// interior [1,3,6,7,6,3,1]/27; boundary rows via cm1/c0/cp1 overrides.
// ---------------------------------------------------------------------------
__device__ __forceinline__ void coef(int g, float& cm1, float& c0, float& cp1)
{
    cm1 = (g == 1 || g == 127) ? 5.f : 6.f;
    c0  = (g == 0 || g == 127) ? 4.f : 7.f;
    cp1 = (g == 0 || g == 126) ? 5.f : 6.f;
}

// ---------------------------------------------------------------------------
// Fused tile kernel over ALL 32768 x-pairs.
//   inactive pair -> write its 16x8x8 zeros (replaces zero_out for that tile)
//   active pair   -> splat points into 22x14x14 LDS tile, then smooth
//                    z/y/x IN PLACE with per-column register rolling.
// In-place safety: output index g only overwrites input g, which no later
// output of the same column reads (out[g+1] needs g+1..g+7); columns are
// thread-private so there is no cross-thread hazard.
// LDS = 34,496 B (raw only, zs eliminated) -> 4 blocks/CU, 32 waves/CU.
// ---------------------------------------------------------------------------
__global__ __launch_bounds__(512, 8)
void tile_all(const float4* __restrict__ pts,
              const unsigned char* __restrict__ flags,
              float* __restrict__ out)
{
    __shared__ float2 raw[14 * 14 * 22];   // 34,496 B

    const int code = blockIdx.x;
    const int pair = code & 7;
    const int ty   = (code >> 3) & 15;
    const int tz   = (code >> 7) & 15;
    const int b    = code >> 11;
    const int Tx = pair * 16, Ty = ty * 8, Tz = tz * 8;
    const int t = threadIdx.x;

    float* ob = out + (((size_t)(b * NVOX + Tz) * NVOX + Ty) * NVOX + Tx);

    const unsigned short fl = ((const unsigned short*)flags)[code];
    if (fl == 0) {
        // no point within reach of this pair: exact zeros, 256 float4 stores
        if (t < 256) {
            int x4 = t & 3, y = (t >> 2) & 7, z = t >> 5;
            *(float4*)&ob[((size_t)z * NVOX + y) * NVOX + x4 * 4] =
                make_float4(0.f, 0.f, 0.f, 0.f);
        }
        return;
    }

    {   // zero the LDS tile (float4 fill)
        float4* rz = (float4*)raw;
        for (int u = t; u < 2156; u += 512) rz[u] = make_float4(0.f, 0.f, 0.f, 0.f);
    }
    __syncthreads();

    // scatter this batch's points (raw covers [T-3, T+{19,11,11}))
    const float4* pb = pts + b * NPT;
    for (int p = t; p < NPT; p += 512) {
        float4 pt = pb[p];
        float x0f = floorf(pt.x), y0f = floorf(pt.y), z0f = floorf(pt.z);
        int x0 = (int)x0f, y0 = (int)y0f, z0 = (int)z0f;
        int lx0 = x0 - Tx + 3, ly0 = y0 - Ty + 3, lz0 = z0 - Tz + 3;
        if (lx0 + 1 < 0 || lx0 > 21 || ly0 + 1 < 0 || ly0 > 13 ||
            lz0 + 1 < 0 || lz0 > 13) continue;
        float fx = pt.x - x0f, fy = pt.y - y0f, fz = pt.z - z0f;
        float val = pt.w;
        #pragma unroll
        for (int dz = 0; dz < 2; ++dz) {
            int zi = z0 + dz, lz = lz0 + dz;
            if ((unsigned)zi >= 128u || (unsigned)lz >= 14u) continue;
            float wz = dz ? fz : 1.f - fz;
            #pragma unroll
            for (int dy = 0; dy < 2; ++dy) {
                int yi = y0 + dy, ly = ly0 + dy;
                if ((unsigned)yi >= 128u || (unsigned)ly >= 14u) continue;
                float wy = dy ? fy : 1.f - fy;
                #pragma unroll
                for (int dx = 0; dx < 2; ++dx) {
                    int xi = x0 + dx, lx = lx0 + dx;
                    if ((unsigned)xi >= 128u || (unsigned)lx >= 22u) continue;
                    float w = (dx ? fx : 1.f - fx) * wy * wz;
                    float2* cell = &raw[(lz * 14 + ly) * 22 + lx];
                    atomicAdd(&cell->x, w * val);
                    atomicAdd(&cell->y, w);
                }
            }
        }
    }
    __syncthreads();

    // z-pass IN PLACE: column (ly,lx) = t, stride 308. 14 reads -> 8 outputs.
    if (t < 308) {
        float2 w0 = raw[t],           w1 = raw[t + 308],     w2 = raw[t + 2 * 308],
               w3 = raw[t + 3 * 308], w4 = raw[t + 4 * 308], w5 = raw[t + 5 * 308],
               w6 = raw[t + 6 * 308];
        #pragma unroll
        for (int z = 0; z < 8; ++z) {
            float cm1, c0, cp1; coef(Tz + z, cm1, c0, cp1);
            float sx = (w0.x + w6.x) + 3.f * (w1.x + w5.x)
                     + cm1 * w2.x + c0 * w3.x + cp1 * w4.x;
            float sy = (w0.y + w6.y) + 3.f * (w1.y + w5.y)
                     + cm1 * w2.y + c0 * w3.y + cp1 * w4.y;
            float2 nxt = raw[t + ((z < 7) ? z + 7 : 7) * 308];  // in-bounds; dummy at z=7
            raw[t + z * 308] = f2(sx * (1.f / 27.f), sy * (1.f / 27.f));
            w0 = w1; w1 = w2; w2 = w3; w3 = w4; w4 = w5; w5 = w6; w6 = nxt;
        }
    }
    __syncthreads();

    // y-pass IN PLACE: column (z,lx), z<8, stride 22. 14 reads -> 8 outputs.
    if (t < 176) {
        int z = t / 22, lx = t - z * 22;
        float2* base = &raw[z * 308 + lx];
        float2 w0 = base[0],      w1 = base[22],     w2 = base[2 * 22],
               w3 = base[3 * 22], w4 = base[4 * 22], w5 = base[5 * 22],
               w6 = base[6 * 22];
        #pragma unroll
        for (int y = 0; y < 8; ++y) {
            float cm1, c0, cp1; coef(Ty + y, cm1, c0, cp1);
            float sx = (w0.x + w6.x) + 3.f * (w1.x + w5.x)
                     + cm1 * w2.x + c0 * w3.x + cp1 * w4.x;
            float sy = (w0.y + w6.y) + 3.f * (w1.y + w5.y)
                     + cm1 * w2.y + c0 * w3.y + cp1 * w4.y;
            float2 nxt = base[((y < 7) ? y + 7 : 7) * 22];      // in-bounds; dummy at y=7
            base[y * 22] = f2(sx * (1.f / 27.f), sy * (1.f / 27.f));
            w0 = w1; w1 = w2; w2 = w3; w3 = w4; w4 = w5; w5 = w6; w6 = nxt;
        }
    }
    __syncthreads();

    // x-pass + division: 2 threads per (z,y) row, 8 outputs each, rolling window
    if (t < 128) {
        int row = t >> 1, half = t & 1;
        int z = row >> 3, y = row & 7;
        const float2* a = &raw[z * 308 + y * 22 + half * 8];
        float2 w0 = a[0], w1 = a[1], w2 = a[2], w3 = a[3],
               w4 = a[4], w5 = a[5], w6 = a[6];
        float res[8];
        #pragma unroll
        for (int i = 0; i < 8; ++i) {
            int x = half * 8 + i;
            float cm1, c0, cp1; coef(Tx + x, cm1, c0, cp1);
            float sx = (w0.x + w6.x) + 3.f * (w1.x + w5.x)
                     + cm1 * w2.x + c0 * w3.x + cp1 * w4.x;
            float sy = (w0.y + w6.y) + 3.f * (w1.y + w5.y)
                     + cm1 * w2.y + c0 * w3.y + cp1 * w4.y;
            res[i] = (sx * (1.f / 27.f)) / (sy * (1.f / 27.f) + 0.001f);
            float2 nxt = a[(i < 7) ? i + 7 : 13];               // in-bounds; dummy at i=7
            w0 = w1; w1 = w2; w2 = w3; w3 = w4; w4 = w5; w5 = w6; w6 = nxt;
        }
        float* orow = &ob[((size_t)z * NVOX + y) * NVOX + half * 8];
        *(float4*)&orow[0] = make_float4(res[0], res[1], res[2], res[3]);
        *(float4*)&orow[4] = make_float4(res[4], res[5], res[6], res[7]);
    }
}

// ---------------------------------------------------------------------------
extern "C" void kernel_launch(void* const* d_in, const int* in_sizes, int n_in,
                              void* d_out, int out_size, void* d_ws, size_t ws_size,
                              hipStream_t stream)
{
    const float* q    = (const float*)d_in[0];
    const float* qval = (const float*)d_in[1];
    const float* w1   = (const float*)d_in[2];
    const float* b1   = (const float*)d_in[3];
    const float* w2   = (const float*)d_in[4];
    const float* b2   = (const float*)d_in[5];
    const float* w3   = (const float*)d_in[6];
    const float* b3   = (const float*)d_in[7];
    const float* w4   = (const float*)d_in[8];
    const float* b4   = (const float*)d_in[9];
    const float* w5   = (const float*)d_in[10];
    const float* b5   = (const float*)d_in[11];
    float* out = (float*)d_out;

    // ws layout:
    //   [0,      65536)  flags (16^3 tiles x 16 batches)
    //   [65536, 557056)  pts  (1920*16 float4)
    //   [557056,679936)  x1g  (1920*16 floats)
    unsigned char* flags = (unsigned char*)d_ws;
    float4* pts = (float4*)((char*)d_ws + 65536);
    float*  x1g = (float*)((char*)d_ws + 557056);

    hipMemsetAsync(d_ws, 0, 65536, stream);

    mlp_stage1<<<240, 256, 0, stream>>>(q, w1, b1, x1g);

    mlp_tail<<<NB, 256, 0, stream>>>(x1g, qval, w2, b2, w3, b3,
                                     w4, b4, w5, b5, pts, flags);

    tile_all<<<NPAIRS, 512, 0, stream>>>(pts, flags, out);
}

// Round 2
// 233.350 us; speedup vs baseline: 1.1958x; 1.1958x over previous
//
#include <hip/hip_runtime.h>
#include <cstddef>

// Problem constants
#define NB 16
#define NVOX 128
#define NPT 1920
#define NPAIRS 32768   // 16 b * 16 tz * 16 ty * 8 x-pairs

static __device__ __forceinline__ float2 f2(float a, float b) {
    float2 r; r.x = a; r.y = b; return r;
}

// ---------------------------------------------------------------------------
// Zero the whole output at full write BW. grid 4096 x 256, float4 stores.
// Active tiles get overwritten by tile_persist later (~16 MB extra, ~3 us).
// ---------------------------------------------------------------------------
__global__ __launch_bounds__(256)
void zero_out(float4* __restrict__ out)
{
    int idx = blockIdx.x * 2048 + threadIdx.x;
    #pragma unroll
    for (int i = 0; i < 8; ++i)
        out[idx + i * 256] = make_float4(0.f, 0.f, 0.f, 0.f);
}

// ---------------------------------------------------------------------------
// Stage 1: Conv1d(256,240,1) on the (256,8) view, all 16 batches.
// One block per output channel o (240 blocks). w1 row staged coalesced in LDS;
// thread = (half, b, l) computes a split-K partial; pair-combined at the end.
// x1g layout: [b][o*8+l]  (matches (240,8) == (64,30) flat view downstream).
// ---------------------------------------------------------------------------
__global__ __launch_bounds__(256)
void mlp_stage1(const float* __restrict__ q, const float* __restrict__ w1,
                const float* __restrict__ b1, float* __restrict__ x1g)
{
    __shared__ float wrow[256];
    __shared__ float psum[256];
    const int o = blockIdx.x;
    const int t = threadIdx.x;

    wrow[t] = w1[o * 256 + t];
    __syncthreads();

    const int half = t >> 7;       // K-split: i in [half*128, half*128+128)
    const int bl = t & 127;
    const int b = bl >> 3, l = bl & 7;
    const float* qb = q + b * 2048 + l + half * 1024;  // q[b][i*8+l]
    float s = 0.f;
    #pragma unroll 8
    for (int i = 0; i < 128; ++i)
        s = fmaf(wrow[half * 128 + i], qb[i * 8], s);
    psum[t] = s;
    __syncthreads();

    if (t < 128) {
        int bb = t >> 3, ll = t & 7;
        x1g[bb * 1920 + o * 8 + ll] = b1[o] + psum[t] + psum[t + 128];
    }
}

// ---------------------------------------------------------------------------
// Tail: IN chains + grouped convs + point generation + active-tile flags.
// One block per batch, 1024 threads (16 waves) so every barrier-separated
// stage has 4x fewer trips than the 256-thread version; 16 waves pipeline
// the LDS latency.
// ---------------------------------------------------------------------------
__global__ __launch_bounds__(1024)
void mlp_tail(const float* __restrict__ x1g, const float* __restrict__ qval,
              const float* __restrict__ w2, const float* __restrict__ b2,
              const float* __restrict__ w3, const float* __restrict__ b3,
              const float* __restrict__ w4, const float* __restrict__ b4,
              const float* __restrict__ w5, const float* __restrict__ b5,
              float4* __restrict__ pts, unsigned char* __restrict__ flags)
{
    __shared__ float bufA[7680];
    __shared__ float bufC[3840];
    __shared__ float psum[1024], psq[1024];
    __shared__ float meanv[64], rstdv[64];
    __shared__ float m4[16], r4[16];

    const int b = blockIdx.x;
    const int t = threadIdx.x;

    for (int u = t; u < 1920; u += 1024) bufA[u] = x1g[b * 1920 + u];
    __syncthreads();

    // IN1 over (64,30): 16 threads/channel
    {
        int c = t >> 4, g = t & 15;
        float s = 0.f, s2 = 0.f;
        for (int p = g; p < 30; p += 16) { float v = bufA[c * 30 + p]; s += v; s2 += v * v; }
        psum[t] = s; psq[t] = s2;
    }
    __syncthreads();
    if (t < 64) {
        float s = 0.f, s2 = 0.f;
        for (int g = 0; g < 16; ++g) { s += psum[t * 16 + g]; s2 += psq[t * 16 + g]; }
        float m = s * (1.f / 30.f);
        float var = s2 * (1.f / 30.f) - m * m;
        meanv[t] = m; rstdv[t] = rsqrtf(var + 1e-5f);
    }
    __syncthreads();
    for (int k = t; k < 1920; k += 1024) {
        int c = k / 30;
        bufA[k] = fmaxf((bufA[k] - meanv[c]) * rstdv[c], 0.f);
    }
    __syncthreads();

    // stage2: grouped conv 64->128, flat (32,120) in bufC
    for (int m = t; m < 3840; m += 1024) {
        int c = m / 60;
        int r = m - c * 60;
        int j = r / 30;
        int p = r - j * 30;
        bufC[m] = fmaf(bufA[c * 30 + p], w2[c * 2 + j], b2[c * 2 + j]);
    }
    __syncthreads();
    // IN2 over (32,120): 32 threads/channel
    {
        int c = t >> 5, g = t & 31;
        float s = 0.f, s2 = 0.f;
        for (int p = g; p < 120; p += 32) { float v = bufC[c * 120 + p]; s += v; s2 += v * v; }
        psum[t] = s; psq[t] = s2;
    }
    __syncthreads();
    if (t < 32) {
        float s = 0.f, s2 = 0.f;
        for (int g = 0; g < 32; ++g) { s += psum[t * 32 + g]; s2 += psq[t * 32 + g]; }
        float m = s * (1.f / 120.f);
        float var = s2 * (1.f / 120.f) - m * m;
        meanv[t] = m; rstdv[t] = rsqrtf(var + 1e-5f);
    }
    __syncthreads();
    for (int m = t; m < 3840; m += 1024) {
        int c = m / 120;
        bufC[m] = fmaxf((bufC[m] - meanv[c]) * rstdv[c], 0.f);
    }
    __syncthreads();

    // stage3: grouped conv 32->64, flat (16,480) in bufA
    for (int m = t; m < 7680; m += 1024) {
        int c = m / 240;
        int r = m - c * 240;
        int j = r / 120;
        int p = r - j * 120;
        bufA[m] = fmaf(bufC[c * 120 + p], w3[c * 2 + j], b3[c * 2 + j]);
    }
    __syncthreads();

    // IN3 over (16,480): 64 threads/channel
    const int c3 = t >> 6, g3 = t & 63;
    {
        float s = 0.f, s2 = 0.f;
        for (int p = g3; p < 480; p += 64) { float v = bufA[c3 * 480 + p]; s += v; s2 += v * v; }
        psum[t] = s; psq[t] = s2;
    }
    __syncthreads();
    if (t < 16) {
        float s = 0.f, s2 = 0.f;
        for (int g = 0; g < 64; ++g) { s += psum[t * 64 + g]; s2 += psq[t * 64 + g]; }
        float m = s * (1.f / 480.f);
        float var = s2 * (1.f / 480.f) - m * m;
        meanv[t] = m; rstdv[t] = rsqrtf(var + 1e-5f);
    }
    __syncthreads();
    // normalize+relu in place, accumulate relu'd sums for stage4 stats
    {
        float m = meanv[c3], r = rstdv[c3];
        float s = 0.f, s2 = 0.f;
        for (int p = g3; p < 480; p += 64) {
            int idx = c3 * 480 + p;
            float v = fmaxf((bufA[idx] - m) * r, 0.f);
            bufA[idx] = v; s += v; s2 += v * v;
        }
        psum[t] = s; psq[t] = s2;
    }
    __syncthreads();
    // stage4 IN stats analytically: x4[c, j*480+p] = x3n[c,p]*w4[c,j]+b4[c*4+j]
    if (t < 16) {
        float s = 0.f, s2 = 0.f;
        for (int g = 0; g < 64; ++g) { s += psum[t * 64 + g]; s2 += psq[t * 64 + g]; }
        float sum4 = 0.f, sq4 = 0.f;
        for (int j = 0; j < 4; ++j) {
            float w = w4[t * 4 + j], bb = b4[t * 4 + j];
            sum4 += w * s + 480.f * bb;
            sq4  += w * w * s2 + 2.f * w * bb * s + 480.f * bb * bb;
        }
        float m = sum4 * (1.f / 1920.f);
        float var = sq4 * (1.f / 1920.f) - m * m;
        m4[t] = m; r4[t] = rsqrtf(var + 1e-5f);
    }
    __syncthreads();

    // per-point: stage4 apply + stage5 einsum + tanh + emit point + mark tiles
    for (int l = t; l < NPT; l += 1024) {
        int j = l / 480;
        int p = l - j * 480;
        float a0 = b5[0], a1 = b5[1], a2 = b5[2];
        #pragma unroll
        for (int c = 0; c < 16; ++c) {
            float xv = bufA[c * 480 + p];
            float x4 = fmaf(xv, w4[c * 4 + j], b4[c * 4 + j]);
            float h  = fmaxf((x4 - m4[c]) * r4[c], 0.f);
            a0 = fmaf(w5[c],      h, a0);
            a1 = fmaf(w5[16 + c], h, a1);
            a2 = fmaf(w5[32 + c], h, a2);
        }
        float px = tanhf(a0) * 64.f + 63.5f;
        float py = tanhf(a1) * 64.f + 63.5f;
        float pz = tanhf(a2) * 64.f + 63.5f;
        float val = 1.f / (1.f + expf(-qval[l]));

        float4 pv; pv.x = px; pv.y = py; pv.z = pz; pv.w = val;
        pts[b * NPT + l] = pv;

        int x0 = (int)floorf(px), y0 = (int)floorf(py), z0 = (int)floorf(pz);
        int xlo = max(0, x0 - 3), xhi = min(127, x0 + 4);
        int ylo = max(0, y0 - 3), yhi = min(127, y0 + 4);
        int zlo = max(0, z0 - 3), zhi = min(127, z0 + 4);
        if (xlo > xhi || ylo > yhi || zlo > zhi) continue;
        int txl = xlo >> 3, txh = xhi >> 3;
        int tyl = ylo >> 3, tyh = yhi >> 3;
        int tzl = zlo >> 3, tzh = zhi >> 3;
        for (int tz = tzl; tz <= tzh; ++tz)
            for (int ty = tyl; ty <= tyh; ++ty)
                for (int tx = txl; tx <= txh; ++tx)
                    flags[((b * 16 + tz) * 16 + ty) * 16 + tx] = 1;
    }
}

// ---------------------------------------------------------------------------
// Compact active tile-pairs (read flags as ushort: 2 tiles per x-pair).
// ---------------------------------------------------------------------------
__global__ __launch_bounds__(256)
void compact_tiles(const unsigned char* __restrict__ flags,
                   int* __restrict__ count, int* __restrict__ list)
{
    int i = blockIdx.x * 256 + threadIdx.x;   // pair index 0..32767
    const unsigned short* fp = (const unsigned short*)flags;
    if (fp[i] != 0) {
        int pos = atomicAdd(count, 1);
        list[pos] = i;
    }
}

// ---------------------------------------------------------------------------
// Per-axis composed 7-tap coefficients (A^3, zero-padded 3-tap average):
// interior [1,3,6,7,6,3,1]/27; boundary rows via cm1/c0/cp1 overrides.
// ---------------------------------------------------------------------------
__device__ __forceinline__ void coef(int g, float& cm1, float& c0, float& cp1)
{
    cm1 = (g == 1 || g == 127) ? 5.f : 6.f;
    c0  = (g == 0 || g == 127) ? 4.f : 7.f;
    cp1 = (g == 0 || g == 126) ? 5.f : 6.f;
}

// ---------------------------------------------------------------------------
// Persistent active-tile kernel: 1024 blocks (4/CU exactly at 34.5 KB LDS)
// grid-stride over the compacted list. No workgroup churn: LDS allocated
// 1024 times instead of 32768. Splat into 22x14x14 LDS tile, smooth z/y/x
// IN PLACE with per-column register rolling, divide, store 16x8x8.
// In-place safety: output index g only overwrites input g, which no later
// output of the same column reads; columns are thread-private.
// ---------------------------------------------------------------------------
__global__ __launch_bounds__(512, 8)
void tile_persist(const float4* __restrict__ pts, const int* __restrict__ count,
                  const int* __restrict__ list, float* __restrict__ out)
{
    __shared__ float2 raw[14 * 14 * 22];   // 34,496 B

    const int cnt = *count;
    const int t = threadIdx.x;

    for (int idx = blockIdx.x; idx < cnt; idx += gridDim.x) {
        const int code = list[idx];
        const int pair = code & 7;
        const int ty   = (code >> 3) & 15;
        const int tz   = (code >> 7) & 15;
        const int b    = code >> 11;
        const int Tx = pair * 16, Ty = ty * 8, Tz = tz * 8;

        float* ob = out + (((size_t)(b * NVOX + Tz) * NVOX + Ty) * NVOX + Tx);

        {   // zero the LDS tile (float4 fill)
            float4* rz = (float4*)raw;
            for (int u = t; u < 2156; u += 512) rz[u] = make_float4(0.f, 0.f, 0.f, 0.f);
        }
        __syncthreads();

        // scatter this batch's points (raw covers [T-3, T+{19,11,11}))
        const float4* pb = pts + b * NPT;
        for (int p = t; p < NPT; p += 512) {
            float4 pt = pb[p];
            float x0f = floorf(pt.x), y0f = floorf(pt.y), z0f = floorf(pt.z);
            int x0 = (int)x0f, y0 = (int)y0f, z0 = (int)z0f;
            int lx0 = x0 - Tx + 3, ly0 = y0 - Ty + 3, lz0 = z0 - Tz + 3;
            if (lx0 + 1 < 0 || lx0 > 21 || ly0 + 1 < 0 || ly0 > 13 ||
                lz0 + 1 < 0 || lz0 > 13) continue;
            float fx = pt.x - x0f, fy = pt.y - y0f, fz = pt.z - z0f;
            float val = pt.w;
            #pragma unroll
            for (int dz = 0; dz < 2; ++dz) {
                int zi = z0 + dz, lz = lz0 + dz;
                if ((unsigned)zi >= 128u || (unsigned)lz >= 14u) continue;
                float wz = dz ? fz : 1.f - fz;
                #pragma unroll
                for (int dy = 0; dy < 2; ++dy) {
                    int yi = y0 + dy, ly = ly0 + dy;
                    if ((unsigned)yi >= 128u || (unsigned)ly >= 14u) continue;
                    float wy = dy ? fy : 1.f - fy;
                    #pragma unroll
                    for (int dx = 0; dx < 2; ++dx) {
                        int xi = x0 + dx, lx = lx0 + dx;
                        if ((unsigned)xi >= 128u || (unsigned)lx >= 22u) continue;
                        float w = (dx ? fx : 1.f - fx) * wy * wz;
                        float2* cell = &raw[(lz * 14 + ly) * 22 + lx];
                        atomicAdd(&cell->x, w * val);
                        atomicAdd(&cell->y, w);
                    }
                }
            }
        }
        __syncthreads();

        // z-pass IN PLACE: column (ly,lx) = t, stride 308. 14 reads -> 8 outputs.
        if (t < 308) {
            float2 w0 = raw[t],           w1 = raw[t + 308],     w2 = raw[t + 2 * 308],
                   w3 = raw[t + 3 * 308], w4 = raw[t + 4 * 308], w5 = raw[t + 5 * 308],
                   w6 = raw[t + 6 * 308];
            #pragma unroll
            for (int z = 0; z < 8; ++z) {
                float cm1, c0, cp1; coef(Tz + z, cm1, c0, cp1);
                float sx = (w0.x + w6.x) + 3.f * (w1.x + w5.x)
                         + cm1 * w2.x + c0 * w3.x + cp1 * w4.x;
                float sy = (w0.y + w6.y) + 3.f * (w1.y + w5.y)
                         + cm1 * w2.y + c0 * w3.y + cp1 * w4.y;
                float2 nxt = raw[t + ((z < 7) ? z + 7 : 7) * 308];  // in-bounds; dummy at z=7
                raw[t + z * 308] = f2(sx * (1.f / 27.f), sy * (1.f / 27.f));
                w0 = w1; w1 = w2; w2 = w3; w3 = w4; w4 = w5; w5 = w6; w6 = nxt;
            }
        }
        __syncthreads();

        // y-pass IN PLACE: column (z,lx), z<8, stride 22. 14 reads -> 8 outputs.
        if (t < 176) {
            int z = t / 22, lx = t - z * 22;
            float2* base = &raw[z * 308 + lx];
            float2 w0 = base[0],      w1 = base[22],     w2 = base[2 * 22],
                   w3 = base[3 * 22], w4 = base[4 * 22], w5 = base[5 * 22],
                   w6 = base[6 * 22];
            #pragma unroll
            for (int y = 0; y < 8; ++y) {
                float cm1, c0, cp1; coef(Ty + y, cm1, c0, cp1);
                float sx = (w0.x + w6.x) + 3.f * (w1.x + w5.x)
                         + cm1 * w2.x + c0 * w3.x + cp1 * w4.x;
                float sy = (w0.y + w6.y) + 3.f * (w1.y + w5.y)
                         + cm1 * w2.y + c0 * w3.y + cp1 * w4.y;
                float2 nxt = base[((y < 7) ? y + 7 : 7) * 22];      // in-bounds; dummy at y=7
                base[y * 22] = f2(sx * (1.f / 27.f), sy * (1.f / 27.f));
                w0 = w1; w1 = w2; w2 = w3; w3 = w4; w4 = w5; w5 = w6; w6 = nxt;
            }
        }
        __syncthreads();

        // x-pass + division: 2 threads per (z,y) row, 8 outputs each
        if (t < 128) {
            int row = t >> 1, half = t & 1;
            int z = row >> 3, y = row & 7;
            const float2* a = &raw[z * 308 + y * 22 + half * 8];
            float2 w0 = a[0], w1 = a[1], w2 = a[2], w3 = a[3],
                   w4 = a[4], w5 = a[5], w6 = a[6];
            float res[8];
            #pragma unroll
            for (int i = 0; i < 8; ++i) {
                int x = half * 8 + i;
                float cm1, c0, cp1; coef(Tx + x, cm1, c0, cp1);
                float sx = (w0.x + w6.x) + 3.f * (w1.x + w5.x)
                         + cm1 * w2.x + c0 * w3.x + cp1 * w4.x;
                float sy = (w0.y + w6.y) + 3.f * (w1.y + w5.y)
                         + cm1 * w2.y + c0 * w3.y + cp1 * w4.y;
                res[i] = (sx * (1.f / 27.f)) / (sy * (1.f / 27.f) + 0.001f);
                float2 nxt = a[(i < 7) ? i + 7 : 13];               // in-bounds; dummy at i=7
                w0 = w1; w1 = w2; w2 = w3; w3 = w4; w4 = w5; w5 = w6; w6 = nxt;
            }
            float* orow = &ob[((size_t)z * NVOX + y) * NVOX + half * 8];
            *(float4*)&orow[0] = make_float4(res[0], res[1], res[2], res[3]);
            *(float4*)&orow[4] = make_float4(res[4], res[5], res[6], res[7]);
        }
        __syncthreads();   // x-pass reads raw; next iteration re-zeroes it
    }
}

// ---------------------------------------------------------------------------
extern "C" void kernel_launch(void* const* d_in, const int* in_sizes, int n_in,
                              void* d_out, int out_size, void* d_ws, size_t ws_size,
                              hipStream_t stream)
{
    const float* q    = (const float*)d_in[0];
    const float* qval = (const float*)d_in[1];
    const float* w1   = (const float*)d_in[2];
    const float* b1   = (const float*)d_in[3];
    const float* w2   = (const float*)d_in[4];
    const float* b2   = (const float*)d_in[5];
    const float* w3   = (const float*)d_in[6];
    const float* b3   = (const float*)d_in[7];
    const float* w4   = (const float*)d_in[8];
    const float* b4   = (const float*)d_in[9];
    const float* w5   = (const float*)d_in[10];
    const float* b5   = (const float*)d_in[11];
    float* out = (float*)d_out;

    // ws layout:
    //   [0,      65536)  flags (16^3 tiles x 16 batches)
    //   [65536,  65540)  count
    //   [65552, 196624)  list (32768 ints)
    //   [196624,688144)  pts  (1920*16 float4)
    //   [688144,811024)  x1g  (1920*16 floats)
    unsigned char* flags = (unsigned char*)d_ws;
    int*    count = (int*)((char*)d_ws + 65536);
    int*    list  = (int*)((char*)d_ws + 65552);
    float4* pts   = (float4*)((char*)d_ws + 196624);
    float*  x1g   = (float*)((char*)d_ws + 688144);

    hipMemsetAsync(d_ws, 0, 65540, stream);

    zero_out<<<4096, 256, 0, stream>>>((float4*)out);

    mlp_stage1<<<240, 256, 0, stream>>>(q, w1, b1, x1g);

    mlp_tail<<<NB, 1024, 0, stream>>>(x1g, qval, w2, b2, w3, b3,
                                      w4, b4, w5, b5, pts, flags);

    compact_tiles<<<NPAIRS / 256, 256, 0, stream>>>(flags, count, list);

    tile_persist<<<1024, 512, 0, stream>>>(pts, count, list, out);
}